// Round 6
// baseline (218.399 us; speedup 1.0000x reference)
//
#include <hip/hip_runtime.h>

typedef unsigned short ushort_t;
typedef __attribute__((ext_vector_type(8))) short bf16x8;
typedef __attribute__((ext_vector_type(16))) float f32x16;
typedef __attribute__((ext_vector_type(4))) unsigned short ushort4v;

// Problem constants
constexpr int BATCH = 32, CIN = 128, H = 56, W = 56, COUT = 256;
constexpr int HP = 58, WP = 58;
constexpr int KTOT = CIN * 9;                                        // 1152
constexpr size_t WB_BYTES = (size_t)COUT * KTOT * 2;                 // 589824
// xp2 chunk-major: [c8=16][b=32][h=58][w=58][8ch]
constexpr int PLANE = BATCH * HP * WP;                               // 107648 chunks per c8
constexpr size_t XP_BYTES = (size_t)16 * PLANE * 8 * 2;              // 27,557,888

__device__ inline ushort_t f2bf(float f) {
  union { float fl; unsigned u; } v; v.fl = f;
  unsigned u = v.u;
  return (ushort_t)((u + 0x7fffu + ((u >> 16) & 1u)) >> 16);  // RNE
}

// ---------------- pre-pass kernels ----------------

// W [256][128][3][3] f32 -> Wb2 [t=18][kblk=8][cout=256][8] bf16
// (t = pos*2+half; cin = half*64 + kblk*8 + c)
__global__ void conv_w(const float* __restrict__ Ws, ushort_t* __restrict__ Wb2) {
  int idx = blockIdx.x * 256 + threadIdx.x;      // < 294912
  int c = idx & 7;
  int cout = (idx >> 3) & 255;
  int kb = (idx >> 11) & 7;
  int t = idx >> 14;                             // 0..17
  int pos = t >> 1, half = t & 1;
  int cin = half * 64 + kb * 8 + c;
  Wb2[idx] = f2bf(Ws[(cout * 128 + cin) * 9 + pos]);
}

// x NCHW f32 -> xp2 [c8][b][h][w][8] bf16, ring zeros written here too.
__global__ void xpad2(const float* __restrict__ x, ushort_t* __restrict__ xp2) {
  __shared__ ushort_t tile[128][58];             // [c][w_padded]
  int bh = blockIdx.x;                           // 0..32*58-1
  int b = bh / 58, h = bh - b * 58;              // h padded 0..57
  bool interior = (h >= 1 && h <= 56);
  if (interior) {
    int hIn = h - 1;
    const float4* x4 = (const float4*)x;
    {  // zero pad columns
      int ch = threadIdx.x & 127, side = threadIdx.x >> 7;
      tile[ch][side * 57] = 0;
    }
    for (int it = 0; it < 7; ++it) {
      int i = it * 256 + (int)threadIdx.x;       // < 1792 = 128ch * 14
      int ch = i / 14, q = i - ch * 14;
      float4 v = x4[(size_t)(b * 128 + ch) * 784 + hIn * 14 + q];
      int wb = 1 + q * 4;
      tile[ch][wb + 0] = f2bf(v.x);
      tile[ch][wb + 1] = f2bf(v.y);
      tile[ch][wb + 2] = f2bf(v.z);
      tile[ch][wb + 3] = f2bf(v.w);
    }
  }
  __syncthreads();
  ushort4v* o4 = (ushort4v*)xp2;
  for (int it = 0; it < 8; ++it) {
    int i = it * 256 + (int)threadIdx.x;
    if (i >= 1856) break;                        // 16 c8 * 116 ushort4
    int c8 = i / 116, r = i - c8 * 116;
    int w = r >> 1, hf = r & 1;
    ushort4v v;
    if (interior) {
      int ch = c8 * 8 + hf * 4;
      v.x = tile[ch + 0][w];
      v.y = tile[ch + 1][w];
      v.z = tile[ch + 2][w];
      v.w = tile[ch + 3][w];
    } else {
      v.x = v.y = v.z = v.w = 0;
    }
    o4[((size_t)((c8 * 32 + b) * 58 + h) * 58 + w) * 2 + hf] = v;
  }
}

// ---------------- main implicit-GEMM kernel ----------------
// C[cout][pix] = sum_k Wb[cout][k] * im2col[k][pix].
// Tile BM=256 x BN=256, BK=64, 18 K-tiles. 512 thr = 8 waves (2M x 4N),
// per-wave 128x64 = 4x2 units of 32x32, mfma_f32_32x32x16_bf16 (2495 TF rate).
// LDS 128 KB: 2 buf x (A 32KB + B 32KB), chunk-major [kb=8][elem=256][8ch].
// Frag read: kb=(ks*2+(lane>>5)), elem=(l&31)+unit*32 -> two 512B contiguous
// segments per wave read, conflict-free, no swizzle.
// R4-verified counted-vmcnt schedule: stage tile t+2 after barrier, vmcnt(8)
// at iter end waits tile t+1 only (never 0 mid-loop).
// XCD swizzle: 392 = 8*49 exact -> each XCD works 49 contiguous pixel-tiles.

__global__ __launch_bounds__(512) void conv_mfma(
    const ushort_t* __restrict__ Wb2, const ushort_t* __restrict__ xp2,
    const float* __restrict__ bias, float* __restrict__ out) {
  __shared__ ushort_t ldsA[2][16384];
  __shared__ ushort_t ldsB[2][16384];

  const int tid = threadIdx.x;
  const int lane = tid & 63;
  const int wid = tid >> 6;
  const int wm = wid >> 2, wn = wid & 3;          // 2M x 4N wave grid
  const int l5 = lane >> 5, l31 = lane & 31;
  const int tileN = ((int)blockIdx.x & 7) * 49 + ((int)blockIdx.x >> 3);

  // ---- per-thread staging sources (constant across K-loop) ----
  const ushort_t* aSrc[4];
  const ushort_t* bSrc[4];
#pragma unroll
  for (int p = 0; p < 4; ++p) {
    int idx = p * 512 + tid;                      // 0..2047 = [kb=8][elem=256]
    aSrc[p] = Wb2 + idx * 8;
    int kb = idx >> 8, pi = idx & 255;
    int pg = tileN * 256 + pi;                    // global output pixel
    int bq = pg / 3136;
    int rem = pg - bq * 3136;
    int hh = rem / 56;
    int ww = rem - hh * 56;
    int pixBase = (bq * 58 + hh) * 58 + ww;       // padded-space chunk index
    bSrc[p] = xp2 + ((size_t)kb * PLANE + pixBase) * 8;
  }
  const int dOff = tid * 8;                       // LDS short offset per 512-chunk

  auto stage = [&](int bb, int t) {
    int pos = t >> 1;
    int kh = pos / 3;
    int kw = pos - kh * 3;
    int aoff = t * 16384;                                      // shorts
    int boff = (t & 1) * (8 * PLANE * 8) + (kh * 58 + kw) * 8; // shorts
    ushort_t* dA = &ldsA[bb][0];
    ushort_t* dB = &ldsB[bb][0];
#pragma unroll
    for (int p = 0; p < 4; ++p) {
      __builtin_amdgcn_global_load_lds(
          (const __attribute__((address_space(1))) unsigned int*)(aSrc[p] + aoff),
          (__attribute__((address_space(3))) unsigned int*)(dA + p * 4096 + dOff),
          16, 0, 0);
      __builtin_amdgcn_global_load_lds(
          (const __attribute__((address_space(1))) unsigned int*)(bSrc[p] + boff),
          (__attribute__((address_space(3))) unsigned int*)(dB + p * 4096 + dOff),
          16, 0, 0);
    }
  };

  f32x16 acc[4][2] = {};

  // fragment base offsets (shorts): + unit*256 + (ks*2+l5)*2048
  const int aBase = (wm * 128 + l31) * 8;
  const int bBase = (wn * 64 + l31) * 8;

  // ---- prologue: tiles 0 and 1 in flight ----
  stage(0, 0);
  stage(1, 1);
  asm volatile("s_waitcnt vmcnt(8)" ::: "memory");   // tile 0 landed
  __builtin_amdgcn_s_barrier();

  for (int t = 0; t < 18; ++t) {
    const int p = t & 1;
    const ushort_t* A0 = &ldsA[p][0];
    const ushort_t* B0 = &ldsB[p][0];

    // ---- phase A: ks 0,1 ----
    bf16x8 a01[2][4], b01[2][2];
#pragma unroll
    for (int ks = 0; ks < 2; ++ks) {
      const int kb = (ks * 2 + l5) * 2048;
#pragma unroll
      for (int mu = 0; mu < 4; ++mu)
        a01[ks][mu] = *(const bf16x8*)(A0 + kb + aBase + mu * 256);
#pragma unroll
      for (int nu = 0; nu < 2; ++nu)
        b01[ks][nu] = *(const bf16x8*)(B0 + kb + bBase + nu * 256);
    }
#pragma unroll
    for (int ks = 0; ks < 2; ++ks)
#pragma unroll
      for (int mu = 0; mu < 4; ++mu)
#pragma unroll
        for (int nu = 0; nu < 2; ++nu)
          acc[mu][nu] = __builtin_amdgcn_mfma_f32_32x32x16_bf16(
              a01[ks][mu], b01[ks][nu], acc[mu][nu], 0, 0, 0);

    // ---- phase B fragments: ks 2,3 ----
    bf16x8 a23[2][4], b23[2][2];
#pragma unroll
    for (int ks = 0; ks < 2; ++ks) {
      const int kb = ((ks + 2) * 2 + l5) * 2048;
#pragma unroll
      for (int mu = 0; mu < 4; ++mu)
        a23[ks][mu] = *(const bf16x8*)(A0 + kb + aBase + mu * 256);
#pragma unroll
      for (int nu = 0; nu < 2; ++nu)
        b23[ks][nu] = *(const bf16x8*)(B0 + kb + bBase + nu * 256);
    }

    // all reads of buf[p] complete, then free it for tile t+2
    asm volatile("s_waitcnt lgkmcnt(0)" ::: "memory");
    __builtin_amdgcn_sched_barrier(0);
    __builtin_amdgcn_s_barrier();
    __builtin_amdgcn_sched_barrier(0);
    if (t < 16) stage(p, t + 2);

    __builtin_amdgcn_s_setprio(1);
#pragma unroll
    for (int ks = 0; ks < 2; ++ks)
#pragma unroll
      for (int mu = 0; mu < 4; ++mu)
#pragma unroll
        for (int nu = 0; nu < 2; ++nu)
          acc[mu][nu] = __builtin_amdgcn_mfma_f32_32x32x16_bf16(
              a23[ks][mu], b23[ks][nu], acc[mu][nu], 0, 0, 0);
    __builtin_amdgcn_s_setprio(0);

    // wait tile t+1 only (t+2's 8 loads stay in flight)
    if (t < 16) {
      asm volatile("s_waitcnt vmcnt(8)" ::: "memory");
    } else if (t == 16) {
      asm volatile("s_waitcnt vmcnt(0)" ::: "memory");
    }
    __builtin_amdgcn_s_barrier();
  }

  // ---- epilogue: 32x32 C/D layout: col = l31 (pixel), row(cout) =
  //      wm*128 + mu*32 + (r&3) + 8*(r>>2) + 4*l5 ----
#pragma unroll
  for (int nu = 0; nu < 2; ++nu) {
    int pgo = tileN * 256 + wn * 64 + nu * 32 + l31;
    int bq2 = pgo / 3136;
    int rem2 = pgo - bq2 * 3136;
    float* op = out + (size_t)bq2 * 256 * 3136 + rem2;
#pragma unroll
    for (int mu = 0; mu < 4; ++mu)
#pragma unroll
      for (int r = 0; r < 16; ++r) {
        int co = wm * 128 + mu * 32 + (r & 3) + 8 * (r >> 2) + 4 * l5;
        op[(size_t)co * 3136] = acc[mu][nu][r] + bias[co];
      }
  }
}

// ---------------- fallback (ws too small): direct fp32 conv ----------------
__global__ void conv_naive(const float* __restrict__ x, const float* __restrict__ Wt,
                           const float* __restrict__ bias, float* __restrict__ out, int total) {
  int idx = blockIdx.x * 256 + threadIdx.x;
  if (idx >= total) return;
  int w = idx % 56;
  int t1 = idx / 56;
  int h = t1 % 56;
  int t2 = t1 / 56;
  int co = t2 % 256;
  int b = t2 / 256;
  float acc = bias[co];
  for (int c = 0; c < 128; ++c)
    for (int kh = 0; kh < 3; ++kh) {
      int ih = h + kh - 1;
      if (ih < 0 || ih >= 56) continue;
      for (int kw = 0; kw < 3; ++kw) {
        int iw = w + kw - 1;
        if (iw < 0 || iw >= 56) continue;
        acc += x[((b * 128 + c) * 56 + ih) * 56 + iw] * Wt[((co * 128 + c) * 3 + kh) * 3 + kw];
      }
    }
  out[idx] = acc;
}

extern "C" void kernel_launch(void* const* d_in, const int* in_sizes, int n_in,
                              void* d_out, int out_size, void* d_ws, size_t ws_size,
                              hipStream_t stream) {
  const float* x = (const float*)d_in[0];
  const float* Wt = (const float*)d_in[1];
  const float* bias = (const float*)d_in[2];
  float* out = (float*)d_out;

  const size_t need = WB_BYTES + XP_BYTES;   // ~28.1 MB
  if (ws_size < need) {
    int total = BATCH * COUT * H * W;
    conv_naive<<<(total + 255) / 256, 256, 0, stream>>>(x, Wt, bias, out, total);
    return;
  }
  ushort_t* Wb2 = (ushort_t*)d_ws;
  ushort_t* xp2 = (ushort_t*)((char*)d_ws + WB_BYTES);

  conv_w<<<1152, 256, 0, stream>>>(Wt, Wb2);
  xpad2<<<32 * 58, 256, 0, stream>>>(x, xp2);
  conv_mfma<<<392, 512, 0, stream>>>(Wb2, xp2, bias, out);
}

// Round 8
// 218.214 us; speedup vs baseline: 1.0008x; 1.0008x over previous
//
#include <hip/hip_runtime.h>

typedef unsigned short ushort_t;
typedef __attribute__((ext_vector_type(8))) short bf16x8;
typedef __attribute__((ext_vector_type(4))) float f32x4;
typedef __attribute__((ext_vector_type(4))) unsigned short ushort4v;

// Problem constants
constexpr int BATCH = 32, CIN = 128, H = 56, W = 56, COUT = 256;
constexpr int HP = 58, WP = 58;
constexpr int KTOT = CIN * 9;                                        // 1152
constexpr size_t WB_BYTES = (size_t)COUT * KTOT * 2;                 // 589824
// xp2 chunk-major: [c8=16][b=32][h=58][w=58][8ch]
constexpr int PLANE = BATCH * HP * WP;                               // 107648 chunks per c8
constexpr size_t XP_BYTES = (size_t)16 * PLANE * 8 * 2;              // 27,557,888

__device__ inline ushort_t f2bf(float f) {
  union { float fl; unsigned u; } v; v.fl = f;
  unsigned u = v.u;
  return (ushort_t)((u + 0x7fffu + ((u >> 16) & 1u)) >> 16);  // RNE
}

// ---------------- pre-pass kernels ----------------

// W [256][128][3][3] f32 -> Wb2 [t=18][kblk=8][cout=256][8] bf16
// (t = pos*2+half; cin = half*64 + kblk*8 + c)
__global__ void conv_w(const float* __restrict__ Ws, ushort_t* __restrict__ Wb2) {
  int idx = blockIdx.x * 256 + threadIdx.x;      // < 294912
  int c = idx & 7;
  int cout = (idx >> 3) & 255;
  int kb = (idx >> 11) & 7;
  int t = idx >> 14;                             // 0..17
  int pos = t >> 1, half = t & 1;
  int cin = half * 64 + kb * 8 + c;
  Wb2[idx] = f2bf(Ws[(cout * 128 + cin) * 9 + pos]);
}

// x NCHW f32 -> xp2 [c8][b][h][w][8] bf16, ring zeros written here too.
__global__ void xpad2(const float* __restrict__ x, ushort_t* __restrict__ xp2) {
  __shared__ ushort_t tile[128][58];             // [c][w_padded]
  int bh = blockIdx.x;                           // 0..32*58-1
  int b = bh / 58, h = bh - b * 58;              // h padded 0..57
  bool interior = (h >= 1 && h <= 56);
  if (interior) {
    int hIn = h - 1;
    const float4* x4 = (const float4*)x;
    {  // zero pad columns
      int ch = threadIdx.x & 127, side = threadIdx.x >> 7;
      tile[ch][side * 57] = 0;
    }
    for (int it = 0; it < 7; ++it) {
      int i = it * 256 + (int)threadIdx.x;       // < 1792 = 128ch * 14
      int ch = i / 14, q = i - ch * 14;
      float4 v = x4[(size_t)(b * 128 + ch) * 784 + hIn * 14 + q];
      int wb = 1 + q * 4;
      tile[ch][wb + 0] = f2bf(v.x);
      tile[ch][wb + 1] = f2bf(v.y);
      tile[ch][wb + 2] = f2bf(v.z);
      tile[ch][wb + 3] = f2bf(v.w);
    }
  }
  __syncthreads();
  ushort4v* o4 = (ushort4v*)xp2;
  for (int it = 0; it < 8; ++it) {
    int i = it * 256 + (int)threadIdx.x;
    if (i >= 1856) break;                        // 16 c8 * 116 ushort4
    int c8 = i / 116, r = i - c8 * 116;
    int w = r >> 1, hf = r & 1;
    ushort4v v;
    if (interior) {
      int ch = c8 * 8 + hf * 4;
      v.x = tile[ch + 0][w];
      v.y = tile[ch + 1][w];
      v.z = tile[ch + 2][w];
      v.w = tile[ch + 3][w];
    } else {
      v.x = v.y = v.z = v.w = 0;
    }
    o4[((size_t)((c8 * 32 + b) * 58 + h) * 58 + w) * 2 + hf] = v;
  }
}

// ---------------- main implicit-GEMM kernel ----------------
// C[cout][pix] = sum_k Wb[cout][k] * im2col[k][pix].
// Tile BM=256 x BN=256, BK=64, 18 K-tiles. 512 thr = 8 waves (2M x 4N),
// per-wave 128x64, mfma 16x16x32 bf16. LDS 128 KB dbuf, chunk-major
// [kb=8][elem=256][8ch], conflict-free lane-linear staging & reads.
// R8: cross-barrier fragment pipelining with CROSS-WAVE-SAFE pre-reads.
// Iter: MFMA ks0 (preloaded) -> read ks1(buf p) -> lgkm0 -> barrier(a) ->
// stage(p,t+2) -> vmcnt(8) -> barrier(b) [all waves' tile-t+1 loads landed]
// -> MFMA ks1 -> pre-read tile-t+1 ks0 (buf p^1) under the ks1 grind.
// vmcnt is per-wave: every LDS read is ordered after a barrier that follows
// ALL waves' vmcnt — this was R7's race, now fixed.

__global__ __launch_bounds__(512, 2) void conv_mfma(
    const ushort_t* __restrict__ Wb2, const ushort_t* __restrict__ xp2,
    const float* __restrict__ bias, float* __restrict__ out) {
  __shared__ ushort_t ldsA[2][16384];
  __shared__ ushort_t ldsB[2][16384];

  const int tid = threadIdx.x;
  const int lane = tid & 63;
  const int wid = tid >> 6;
  const int wm = wid >> 2, wn = wid & 3;          // 2M x 4N wave grid
  const int lg = lane >> 4, lr = lane & 15;
  const int tileN = blockIdx.x;                   // 0..391 (256 pixels each)

  // ---- per-thread staging bases ----
  const ushort_t* aSrc0 = Wb2 + tid * 8;                     // + p*4096 + t*16384
  const ushort_t* bSrc0;                                     // + p*(2*PLANE*8) + boff
  {
    int pg = tileN * 256 + (tid & 255);
    int bq = pg / 3136;
    int rem = pg - bq * 3136;
    int hh = rem / 56;
    int ww = rem - hh * 56;
    int pixBase = (bq * 58 + hh) * 58 + ww;
    bSrc0 = xp2 + ((size_t)(tid >> 8) * PLANE + pixBase) * 8;
  }
  const int dOff = tid * 8;

  auto stage = [&](int bb, int t) {
    int pos = t >> 1;
    int kh = pos / 3;
    int kw = pos - kh * 3;
    const ushort_t* aS = aSrc0 + t * 16384;
    const ushort_t* bS = bSrc0 + (t & 1) * (size_t)(8 * PLANE * 8) + (kh * 58 + kw) * 8;
    ushort_t* dA = &ldsA[bb][0];
    ushort_t* dB = &ldsB[bb][0];
#pragma unroll
    for (int p = 0; p < 4; ++p) {
      __builtin_amdgcn_global_load_lds(
          (const __attribute__((address_space(1))) unsigned int*)(aS + p * 4096),
          (__attribute__((address_space(3))) unsigned int*)(dA + p * 4096 + dOff),
          16, 0, 0);
      __builtin_amdgcn_global_load_lds(
          (const __attribute__((address_space(1))) unsigned int*)(bS + (size_t)p * (2 * PLANE * 8)),
          (__attribute__((address_space(3))) unsigned int*)(dB + p * 4096 + dOff),
          16, 0, 0);
    }
  };

  f32x4 acc[8][4] = {};
  bf16x8 af0[8], bf0[4], af1[8], bf1[4];

  const int aOffT = (wm * 128 + lr) * 8;          // + m*128 + kb*2048
  const int bOffT = (wn * 64 + lr) * 8;           // + n*128 + kb*2048

  // ---- prologue: tiles 0,1 in flight; safe pre-read of tile0 ks0 ----
  stage(0, 0);
  stage(1, 1);
  asm volatile("s_waitcnt vmcnt(8)" ::: "memory");   // own tile-0 loads landed
  __builtin_amdgcn_s_barrier();                      // ALL waves' tile-0 loads landed
  {
    const ushort_t* A0 = &ldsA[0][0];
    const ushort_t* B0 = &ldsB[0][0];
    const int kb = lg * 2048;
#pragma unroll
    for (int m = 0; m < 8; ++m) af0[m] = *(const bf16x8*)(A0 + kb + aOffT + m * 128);
#pragma unroll
    for (int n = 0; n < 4; ++n) bf0[n] = *(const bf16x8*)(B0 + kb + bOffT + n * 128);
  }

  for (int t = 0; t < 18; ++t) {
    const int p = t & 1;
    const ushort_t* A0 = &ldsA[p][0];
    const ushort_t* B0 = &ldsB[p][0];

    // ---- MFMA ks0 (operands pre-read) ----
    __builtin_amdgcn_s_setprio(1);
#pragma unroll
    for (int m = 0; m < 8; ++m)
#pragma unroll
      for (int n = 0; n < 4; ++n)
        acc[m][n] = __builtin_amdgcn_mfma_f32_16x16x32_bf16(af0[m], bf0[n], acc[m][n], 0, 0, 0);
    __builtin_amdgcn_s_setprio(0);

    // ---- read ks1 fragments (buf p) while ks0 pipe grinds ----
    {
      const int kb = (4 + lg) * 2048;
#pragma unroll
      for (int m = 0; m < 8; ++m) af1[m] = *(const bf16x8*)(A0 + kb + aOffT + m * 128);
#pragma unroll
      for (int n = 0; n < 4; ++n) bf1[n] = *(const bf16x8*)(B0 + kb + bOffT + n * 128);
    }

    // all reads of buf[p] (incl. prior pre-reads) complete in every wave,
    // then buf[p] is free for tile t+2
    asm volatile("s_waitcnt lgkmcnt(0)" ::: "memory");
    __builtin_amdgcn_sched_barrier(0);
    __builtin_amdgcn_s_barrier();                   // barrier (a)
    __builtin_amdgcn_sched_barrier(0);
    if (t < 16) stage(p, t + 2);

    // tile t+1 visibility: own-wave vmcnt, then cross-wave barrier
    if (t < 16) {
      asm volatile("s_waitcnt vmcnt(8)" ::: "memory");   // t+1's 8 oldest done
    } else {
      asm volatile("s_waitcnt vmcnt(0)" ::: "memory");
    }
    __builtin_amdgcn_s_barrier();                   // barrier (b)

    // ---- MFMA ks1 ----
    __builtin_amdgcn_s_setprio(1);
#pragma unroll
    for (int m = 0; m < 8; ++m)
#pragma unroll
      for (int n = 0; n < 4; ++n)
        acc[m][n] = __builtin_amdgcn_mfma_f32_16x16x32_bf16(af1[m], bf1[n], acc[m][n], 0, 0, 0);
    __builtin_amdgcn_s_setprio(0);

    // ---- pre-read next tile's ks0 fragments (buf p^1) under ks1 grind ----
    if (t < 17) {
      const ushort_t* A1 = &ldsA[p ^ 1][0];
      const ushort_t* B1 = &ldsB[p ^ 1][0];
      const int kb = lg * 2048;
#pragma unroll
      for (int m = 0; m < 8; ++m) af0[m] = *(const bf16x8*)(A1 + kb + aOffT + m * 128);
#pragma unroll
      for (int n = 0; n < 4; ++n) bf0[n] = *(const bf16x8*)(B1 + kb + bOffT + n * 128);
    }
  }

  // ---- epilogue: row = cout = wm*128 + m*16 + lg*4 + r,  col = pixel ----
  const int cb = wm * 128 + lg * 4;
  float bvv[8][4];
#pragma unroll
  for (int m = 0; m < 8; ++m)
#pragma unroll
    for (int r = 0; r < 4; ++r) bvv[m][r] = bias[cb + m * 16 + r];

#pragma unroll
  for (int n = 0; n < 4; ++n) {
    int pgo = tileN * 256 + wn * 64 + n * 16 + lr;
    int bq2 = pgo / 3136;
    int rem2 = pgo - bq2 * 3136;
    float* op = out + (size_t)bq2 * 256 * 3136 + rem2;
#pragma unroll
    for (int m = 0; m < 8; ++m)
#pragma unroll
      for (int r = 0; r < 4; ++r)
        op[(size_t)(cb + m * 16 + r) * 3136] = acc[m][n][r] + bvv[m][r];
  }
}

// ---------------- fallback (ws too small): direct fp32 conv ----------------
__global__ void conv_naive(const float* __restrict__ x, const float* __restrict__ Wt,
                           const float* __restrict__ bias, float* __restrict__ out, int total) {
  int idx = blockIdx.x * 256 + threadIdx.x;
  if (idx >= total) return;
  int w = idx % 56;
  int t1 = idx / 56;
  int h = t1 % 56;
  int t2 = t1 / 56;
  int co = t2 % 256;
  int b = t2 / 256;
  float acc = bias[co];
  for (int c = 0; c < 128; ++c)
    for (int kh = 0; kh < 3; ++kh) {
      int ih = h + kh - 1;
      if (ih < 0 || ih >= 56) continue;
      for (int kw = 0; kw < 3; ++kw) {
        int iw = w + kw - 1;
        if (iw < 0 || iw >= 56) continue;
        acc += x[((b * 128 + c) * 56 + ih) * 56 + iw] * Wt[((co * 128 + c) * 3 + kh) * 3 + kw];
      }
    }
  out[idx] = acc;
}

extern "C" void kernel_launch(void* const* d_in, const int* in_sizes, int n_in,
                              void* d_out, int out_size, void* d_ws, size_t ws_size,
                              hipStream_t stream) {
  const float* x = (const float*)d_in[0];
  const float* Wt = (const float*)d_in[1];
  const float* bias = (const float*)d_in[2];
  float* out = (float*)d_out;

  const size_t need = WB_BYTES + XP_BYTES;   // ~28.1 MB
  if (ws_size < need) {
    int total = BATCH * COUT * H * W;
    conv_naive<<<(total + 255) / 256, 256, 0, stream>>>(x, Wt, bias, out, total);
    return;
  }
  ushort_t* Wb2 = (ushort_t*)d_ws;
  ushort_t* xp2 = (ushort_t*)((char*)d_ws + WB_BYTES);

  conv_w<<<1152, 256, 0, stream>>>(Wt, Wb2);
  xpad2<<<32 * 58, 256, 0, stream>>>(x, xp2);
  conv_mfma<<<392, 512, 0, stream>>>(Wb2, xp2, bias, out);
}